// Round 1
// baseline (2292.109 us; speedup 1.0000x reference)
//
#include <hip/hip_runtime.h>
#include <hip/hip_fp16.h>

#define T_STEPS 256
#define B_SZ 8
#define HID 256

// ---- workspace layout (float offsets) ----
#define OFF_XW   0                 // (T,B,256) fused input projection  524288
#define OFF_HH   524288            // (T,B,256) hidden history          524288
#define OFF_W1T  1048576           // w1T[k][oc]   27*32
#define OFF_W2T  1049600           // w2T[k][oc]  288*64
#define OFF_W3T  1068032           // w3T[k][oc]  576*128
#define OFF_WFT  1141760           // WfuseT[m][j] 128*256 (= Wi @ enc_w, transposed)
#define OFF_BF   1174528           // bfuse[j] 256 (= ltc_b + Wi @ enc_b)
#define OFF_D1T  1174784           // dec_w1T[k][i] 256*128
#define OFF_D2T  1207552           // dec_w2T[k][i] 128*64
#define OFF_D3T  1215744           // dec_w3T[k][o]  64*6

// ---------------- prep: weight transposes + encoder/Wi fusion ----------------
__global__ __launch_bounds__(256) void prep_kernel(
    const float* __restrict__ conv1_w, const float* __restrict__ conv2_w,
    const float* __restrict__ conv3_w, const float* __restrict__ enc_w,
    const float* __restrict__ enc_b,  const float* __restrict__ ltc_wi,
    const float* __restrict__ ltc_b,  const float* __restrict__ dec_w1,
    const float* __restrict__ dec_w2, const float* __restrict__ dec_w3,
    float* __restrict__ ws)
{
  int gtid = blockIdx.x * 256 + threadIdx.x;
  int nth = gridDim.x * 256;
  // WfuseT[m*256+j] = sum_k ltc_wi[j,k] * enc_w[k,m]
  for (int e = gtid; e < 128 * 256; e += nth) {
    int j = e >> 7, m = e & 127;
    float s = 0.f;
    for (int k = 0; k < 256; ++k) s = fmaf(ltc_wi[j*256 + k], enc_w[k*128 + m], s);
    ws[OFF_WFT + m*256 + j] = s;
  }
  for (int e = gtid; e < 256; e += nth) {
    float s = ltc_b[e];
    for (int k = 0; k < 256; ++k) s = fmaf(ltc_wi[e*256 + k], enc_b[k], s);
    ws[OFF_BF + e] = s;
  }
  for (int e = gtid; e < 27*32;  e += nth) { int k = e>>5, oc = e&31;  ws[OFF_W1T+e] = conv1_w[oc*27 + k]; }
  for (int e = gtid; e < 288*64; e += nth) { int k = e>>6, oc = e&63;  ws[OFF_W2T+e] = conv2_w[oc*288 + k]; }
  for (int e = gtid; e < 576*128;e += nth) { int k = e>>7, oc = e&127; ws[OFF_W3T+e] = conv3_w[oc*576 + k]; }
  for (int e = gtid; e < 256*128;e += nth) { int k = e>>7, i  = e&127; ws[OFF_D1T+e] = dec_w1[i*256 + k]; }
  for (int e = gtid; e < 128*64; e += nth) { int k = e>>6, i  = e&63;  ws[OFF_D2T+e] = dec_w2[i*128 + k]; }
  for (int e = gtid; e < 64*6;   e += nth) { int k = e/6,  o  = e%6;   ws[OFF_D3T+e] = dec_w3[o*64 + k]; }
}

// ---------------- fused per-frame CNN encoder ----------------
// block = one (b,t) frame, 256 threads. Produces xw[t,b,:] = bfuse + Wfuse @ mean_feats
__global__ __launch_bounds__(256) void enc_kernel(
    const float* __restrict__ frames,
    const float* __restrict__ b1, const float* __restrict__ b2,
    const float* __restrict__ b3, float* __restrict__ ws)
{
  __shared__ char smem[65536];
  __half* c1h = (__half*)smem;             // [16][32][32] fp16 (per 16-oc pass)
  __half* c2h = (__half*)(smem + 32768);   // [64][16][16] fp16
  float*  c3s = (float*)smem;              // [128][66] after conv3 (aliases, post-barrier)
  float*  fm  = (float*)(smem + 33792);    // [128]

  const int tid = threadIdx.x;
  const int bt  = blockIdx.x;
  const int b   = bt >> 8;       // T = 256
  const int t   = bt & 255;
  const float* fr  = frames + (size_t)bt * 12288;
  const float* w1T = ws + OFF_W1T;
  const float* w2T = ws + OFF_W2T;
  const float* w3T = ws + OFF_W3T;
  const float* wfT = ws + OFF_WFT;
  const float* bfu = ws + OFF_BF;

  float acc2[64];
  #pragma unroll
  for (int o = 0; o < 64; ++o) acc2[o] = b2[o];

  for (int hp = 0; hp < 2; ++hp) {
    const int ocb = hp * 16;
    // conv1 (stride2 pad1, 3->16 channels this pass), relu, -> LDS fp16
    for (int p = 0; p < 4; ++p) {
      int pos = p * 256 + tid;
      int y = pos >> 5, x = pos & 31;
      float acc[16];
      #pragma unroll
      for (int o = 0; o < 16; ++o) acc[o] = b1[ocb + o];
      for (int ic = 0; ic < 3; ++ic)
        for (int ky = 0; ky < 3; ++ky) {
          int iy = 2*y - 1 + ky;
          bool rok = (unsigned)iy < 64u;
          for (int kx = 0; kx < 3; ++kx) {
            int ix = 2*x - 1 + kx;
            float v = (rok && (unsigned)ix < 64u) ? fr[ic*4096 + iy*64 + ix] : 0.f;
            const float* wp = w1T + (ic*9 + ky*3 + kx) * 32 + ocb;
            #pragma unroll
            for (int o = 0; o < 16; ++o) acc[o] = fmaf(v, wp[o], acc[o]);
          }
        }
      #pragma unroll
      for (int o = 0; o < 16; ++o)
        c1h[o*1024 + pos] = __float2half(fmaxf(acc[o], 0.f));
    }
    __syncthreads();
    // conv2 partial accumulation over these 16 input channels (acc in regs)
    {
      int y = tid >> 4, x = tid & 15;
      for (int icl = 0; icl < 16; ++icl)
        for (int ky = 0; ky < 3; ++ky) {
          int iy = 2*y - 1 + ky;
          bool rok = (unsigned)iy < 32u;
          for (int kx = 0; kx < 3; ++kx) {
            int ix = 2*x - 1 + kx;
            float v = (rok && (unsigned)ix < 32u) ? __half2float(c1h[icl*1024 + iy*32 + ix]) : 0.f;
            const float* wp = w2T + ((hp*16 + icl)*9 + ky*3 + kx) * 64;
            #pragma unroll
            for (int o = 0; o < 64; ++o) acc2[o] = fmaf(v, wp[o], acc2[o]);
          }
        }
    }
    __syncthreads();   // before next pass overwrites c1h
  }
  #pragma unroll
  for (int o = 0; o < 64; ++o) c2h[o*256 + tid] = __float2half(fmaxf(acc2[o], 0.f));
  __syncthreads();
  // conv3: thread = (pos 0..63, ocgroup 0..3)
  const int g = tid >> 6, pos = tid & 63;
  const int y3 = pos >> 3, x3 = pos & 7;
  float acc3[32];
  #pragma unroll
  for (int o = 0; o < 32; ++o) acc3[o] = b3[g*32 + o];
  for (int ic = 0; ic < 64; ++ic)
    for (int ky = 0; ky < 3; ++ky) {
      int iy = 2*y3 - 1 + ky;
      bool rok = (unsigned)iy < 16u;
      for (int kx = 0; kx < 3; ++kx) {
        int ix = 2*x3 - 1 + kx;
        float v = (rok && (unsigned)ix < 16u) ? __half2float(c2h[ic*256 + iy*16 + ix]) : 0.f;
        const float* wp = w3T + (ic*9 + ky*3 + kx) * 128 + g*32;
        #pragma unroll
        for (int o = 0; o < 32; ++o) acc3[o] = fmaf(v, wp[o], acc3[o]);
      }
    }
  __syncthreads();               // all conv3 reads of c2h complete
  #pragma unroll
  for (int o = 0; o < 32; ++o) c3s[(g*32 + o)*66 + pos] = fmaxf(acc3[o], 0.f);
  __syncthreads();
  if (tid < 128) {               // spatial mean per channel
    float s = 0.f;
    for (int p2 = 0; p2 < 64; ++p2) s += c3s[tid*66 + p2];
    fm[tid] = s * (1.f/64.f);
  }
  __syncthreads();
  {
    float accx = bfu[tid];
    for (int m = 0; m < 128; ++m) accx = fmaf(fm[m], wfT[m*256 + tid], accx);
    ws[OFF_XW + (t*B_SZ + b)*HID + tid] = accx;
  }
}

// ---------------- sequential LTC scan: 1 block per batch ----------------
__global__ __launch_bounds__(1024) void scan_kernel(
    const float* __restrict__ wr, const float* __restrict__ tau,
    const float* __restrict__ av, const float* __restrict__ h0,
    float* __restrict__ ws, float* __restrict__ outh)
{
  const int b = blockIdx.x;
  const int tid = threadIdx.x;
  const int j = tid & 255, q = tid >> 8;
  __shared__ float h_s[256];
  __shared__ float part[4][256];
  float4 w4[16];
  const float4* wp = (const float4*)(wr + j*256 + q*64);
  #pragma unroll
  for (int i = 0; i < 16; ++i) w4[i] = wp[i];
  const float tinv = 1.f / tau[j];
  const float aj = av[j];
  if (tid < 256) h_s[tid] = h0[b*256 + tid];
  __syncthreads();
  const float* xw = ws + OFF_XW;
  float* hh = ws + OFF_HH;
  for (int t = 0; t < T_STEPS; ++t) {
    const float4* h4 = (const float4*)(h_s + q*64);
    float s0 = 0.f, s1 = 0.f, s2 = 0.f, s3 = 0.f;
    #pragma unroll
    for (int i = 0; i < 16; ++i) {
      float4 hv = h4[i];
      s0 = fmaf(w4[i].x, hv.x, s0); s1 = fmaf(w4[i].y, hv.y, s1);
      s2 = fmaf(w4[i].z, hv.z, s2); s3 = fmaf(w4[i].w, hv.w, s3);
    }
    part[q][j] = (s0 + s1) + (s2 + s3);
    __syncthreads();
    float pre = part[0][j] + part[1][j] + part[2][j] + part[3][j]
              + xw[(t*B_SZ + b)*HID + j];
    float f = 1.f - 2.f / (1.f + __expf(2.f * pre));
    float hv0 = h_s[j];
    float hn = fmaf(0.1f, fmaf(-(tinv + f), hv0, f * aj), hv0);
    __syncthreads();
    h_s[j] = hn;                       // 4 q-copies write identical value
    if (q == 0) hh[(t*B_SZ + b)*HID + j] = hn;
    __syncthreads();
  }
  if (q == 0) outh[b*HID + j] = h_s[j];
}

// ---------------- decoder MLP over all (t,b), parallel ----------------
__global__ __launch_bounds__(256) void dec_kernel(
    const float* __restrict__ db1, const float* __restrict__ db2,
    const float* __restrict__ db3, const float* __restrict__ ws,
    float* __restrict__ outc)
{
  const int bid = blockIdx.x;
  const int b = bid >> 8, t = bid & 255;
  const int tid = threadIdx.x;
  __shared__ float hloc[256];
  __shared__ float p1[2][128];
  __shared__ float y1s[128];
  __shared__ float p2[4][64];
  __shared__ float y2s[64];
  const float* hh  = ws + OFF_HH + (t*B_SZ + b)*HID;
  const float* d1T = ws + OFF_D1T;
  const float* d2T = ws + OFF_D2T;
  const float* d3T = ws + OFF_D3T;
  hloc[tid] = hh[tid];
  __syncthreads();
  {
    int i = tid & 127, hf = tid >> 7;
    float s = 0.f;
    for (int k = hf*128; k < hf*128 + 128; ++k) s = fmaf(hloc[k], d1T[k*128 + i], s);
    p1[hf][i] = s;
  }
  __syncthreads();
  if (tid < 128) y1s[tid] = fmaxf(p1[0][tid] + p1[1][tid] + db1[tid], 0.f);
  __syncthreads();
  {
    int i = tid & 63, r = tid >> 6;
    float s = 0.f;
    for (int k = r*32; k < r*32 + 32; ++k) s = fmaf(y1s[k], d2T[k*64 + i], s);
    p2[r][i] = s;
  }
  __syncthreads();
  if (tid < 64) y2s[tid] = fmaxf(p2[0][tid] + p2[1][tid] + p2[2][tid] + p2[3][tid] + db2[tid], 0.f);
  __syncthreads();
  if (tid < 6) {
    float s = db3[tid];
    for (int k = 0; k < 64; ++k) s = fmaf(y2s[k], d3T[k*6 + tid], s);
    outc[(b*T_STEPS + t)*6 + tid] = s;
  }
}

extern "C" void kernel_launch(void* const* d_in, const int* in_sizes, int n_in,
                              void* d_out, int out_size, void* d_ws, size_t ws_size,
                              hipStream_t stream)
{
  const float* frames = (const float*)d_in[0];
  const float* h0   = (const float*)d_in[1];
  const float* c1w  = (const float*)d_in[2];
  const float* c1b  = (const float*)d_in[3];
  const float* c2w  = (const float*)d_in[4];
  const float* c2b  = (const float*)d_in[5];
  const float* c3w  = (const float*)d_in[6];
  const float* c3b  = (const float*)d_in[7];
  const float* encw = (const float*)d_in[8];
  const float* encb = (const float*)d_in[9];
  const float* wr   = (const float*)d_in[10];
  const float* wi   = (const float*)d_in[11];
  const float* lb   = (const float*)d_in[12];
  const float* ltau = (const float*)d_in[13];
  const float* la   = (const float*)d_in[14];
  const float* dw1  = (const float*)d_in[15];
  const float* db1  = (const float*)d_in[16];
  const float* dw2  = (const float*)d_in[17];
  const float* db2  = (const float*)d_in[18];
  const float* dw3  = (const float*)d_in[19];
  const float* db3  = (const float*)d_in[20];
  float* out = (float*)d_out;
  float* ws  = (float*)d_ws;

  hipLaunchKernelGGL(prep_kernel, dim3(256), dim3(256), 0, stream,
                     c1w, c2w, c3w, encw, encb, wi, lb, dw1, dw2, dw3, ws);
  hipLaunchKernelGGL(enc_kernel, dim3(2048), dim3(256), 0, stream,
                     frames, c1b, c2b, c3b, ws);
  hipLaunchKernelGGL(scan_kernel, dim3(B_SZ), dim3(1024), 0, stream,
                     wr, ltau, la, h0, ws, out + 12288);
  hipLaunchKernelGGL(dec_kernel, dim3(2048), dim3(256), 0, stream,
                     db1, db2, db3, ws, out);
}